// Round 12
// baseline (277.719 us; speedup 1.0000x reference)
//
#include <hip/hip_runtime.h>
#include <cstdint>
#include <cstddef>

#define DEV __device__ __forceinline__

typedef __bf16 bf16x8 __attribute__((ext_vector_type(8)));
typedef float f32x4 __attribute__((ext_vector_type(4)));
typedef unsigned short ushort8v __attribute__((ext_vector_type(8)));

DEV ushort f2b(float f) {
  uint u = __float_as_uint(f);
  return (ushort)((u + 0x7FFFu + ((u >> 16) & 1u)) >> 16);
}
DEV float bf_lo(uint u) { return __uint_as_float(u << 16); }
DEV float bf_hi(uint u) { return __uint_as_float(u & 0xFFFF0000u); }

// ===== kernel 1: cvt x->bf16 blocks (bx < nCV) + degree-count blocks =====
__global__ __launch_bounds__(256) void k_cvt_count(
    const float* __restrict__ x, ushort* __restrict__ xb, int n8,
    const int* __restrict__ col, int* __restrict__ cnt, int E, int nCV) {
  int b = (int)blockIdx.x, tid = (int)threadIdx.x;
  if (b < nCV) {
    int gsz = nCV * 256;
    for (int i = b * 256 + tid; i < n8; i += gsz) {
      const float* s = x + (size_t)i * 8;
      float4 v0 = *(const float4*)s;
      float4 v1 = *(const float4*)(s + 4);
      ushort8v u;
      u[0] = f2b(v0.x); u[1] = f2b(v0.y); u[2] = f2b(v0.z); u[3] = f2b(v0.w);
      u[4] = f2b(v1.x); u[5] = f2b(v1.y); u[6] = f2b(v1.z); u[7] = f2b(v1.w);
      *(ushort8v*)(xb + (size_t)i * 8) = u;
    }
    return;
  }
  b -= nCV;
  int e = b * 256 + tid;
  if (e < E) atomicAdd(&cnt[col[e]], 1);
}

// ---------------- scan phase A: per-256-chunk scan + dinv ----------------
__global__ __launch_bounds__(256) void k_scanA(const int* __restrict__ cnt,
                                               int* __restrict__ off,
                                               float* __restrict__ dinv,
                                               int* __restrict__ btot, int N) {
  __shared__ int ws[4];
  int t = threadIdx.x, ln = t & 63, wv = t >> 6;
  int i = blockIdx.x * 256 + t;
  int v = (i < N) ? cnt[i] : 0;
  int inc = v;
#pragma unroll
  for (int o = 1; o < 64; o <<= 1) {
    int u = __shfl_up(inc, o);
    if (ln >= o) inc += u;
  }
  if (ln == 63) ws[wv] = inc;
  __syncthreads();
  if (t == 0) {
    int s = 0;
#pragma unroll
    for (int w = 0; w < 4; ++w) { int tmp = ws[w]; ws[w] = s; s += tmp; }
  }
  __syncthreads();
  int excl = ws[wv] + inc - v;
  if (i < N) {
    off[i] = excl;
    dinv[i] = rsqrtf((float)v + 1.0f);
  }
  if (t == 255) btot[blockIdx.x] = excl + v;
}

// -------- scan phase B+C fused: every block rescans btot, applies prefix ----
__global__ __launch_bounds__(256) void k_scanBC(int* __restrict__ off,
                                                const int* __restrict__ btot,
                                                int* __restrict__ cursor,
                                                int N, int E, int NB) {
  __shared__ int ws[4];
  __shared__ int pre_sh[256];
  int t = threadIdx.x, ln = t & 63, wv = t >> 6;
  int v = (t < NB) ? btot[t] : 0;
  int inc = v;
#pragma unroll
  for (int o = 1; o < 64; o <<= 1) {
    int u = __shfl_up(inc, o);
    if (ln >= o) inc += u;
  }
  if (ln == 63) ws[wv] = inc;
  __syncthreads();
  if (t == 0) {
    int s = 0;
#pragma unroll
    for (int w = 0; w < 4; ++w) { int tmp = ws[w]; ws[w] = s; s += tmp; }
  }
  __syncthreads();
  pre_sh[t] = ws[wv] + inc - v;
  __syncthreads();
  int bpre = pre_sh[blockIdx.x];
  int i = blockIdx.x * 256 + t;
  if (i < N) {
    int o = off[i] + bpre;
    off[i] = o;
    cursor[i] = o;
  }
  if (blockIdx.x == 0 && t == 0) off[N] = E;
}

// -------- scatter edges into CSR; payload = (src, dinv[src]) --------
__global__ __launch_bounds__(256) void k_scatter(const int* __restrict__ ei,
                                                 const float* __restrict__ dinv,
                                                 int* __restrict__ cursor,
                                                 int2* __restrict__ edata, int E) {
  int e = blockIdx.x * 256 + threadIdx.x;
  if (e >= E) return;
  int s = ei[e], d = ei[E + e];
  float ws = dinv[s];
  int p = atomicAdd(&cursor[d], 1);
  int2 v; v.x = s; v.y = __float_as_int(ws);
  edata[p] = v;
}

// ========== aggregate x (bf16 gather, 256B/edge) -> xa fp32, s_i ============
// agg commutes with W: only x needs aggregating. Lane covers dims 2l,2l+1.
// acc = sum dinv[s]*x[s]; xa = di*(acc + di*x[node]); s_i = di*(sum dinv[s] + di).
__global__ __launch_bounds__(256) void k_agg_x(
    const ushort* __restrict__ xb, const float* __restrict__ dinv,
    const int* __restrict__ off, const int2* __restrict__ edata,
    float* __restrict__ xa, float* __restrict__ sarr, int N) {
  int wv = __builtin_amdgcn_readfirstlane((int)threadIdx.x >> 6);
  int lane = (int)threadIdx.x & 63;
  int node = blockIdx.x * 4 + wv;
  if (node >= N) return;

  const ushort* gb = xb + 2 * lane;
  int p0 = off[node], p1 = off[node + 1];

  float2 a0 = {0,0}, a1 = {0,0}, a2 = {0,0}, a3 = {0,0};
  float2 a4 = {0,0}, a5 = {0,0}, a6 = {0,0}, a7 = {0,0};
  float sd = 0.f;
  int p = p0;
  for (; p + 8 <= p1; p += 8) {
    int2 e0 = edata[p],     e1 = edata[p + 1], e2 = edata[p + 2], e3 = edata[p + 3];
    int2 e4 = edata[p + 4], e5 = edata[p + 5], e6 = edata[p + 6], e7 = edata[p + 7];
    uint u0 = *(const uint*)(const void*)(gb + (size_t)e0.x * 128);
    uint u1 = *(const uint*)(const void*)(gb + (size_t)e1.x * 128);
    uint u2 = *(const uint*)(const void*)(gb + (size_t)e2.x * 128);
    uint u3 = *(const uint*)(const void*)(gb + (size_t)e3.x * 128);
    uint u4 = *(const uint*)(const void*)(gb + (size_t)e4.x * 128);
    uint u5 = *(const uint*)(const void*)(gb + (size_t)e5.x * 128);
    uint u6 = *(const uint*)(const void*)(gb + (size_t)e6.x * 128);
    uint u7 = *(const uint*)(const void*)(gb + (size_t)e7.x * 128);
    float w0 = __int_as_float(e0.y), w1 = __int_as_float(e1.y);
    float w2 = __int_as_float(e2.y), w3 = __int_as_float(e3.y);
    float w4 = __int_as_float(e4.y), w5 = __int_as_float(e5.y);
    float w6 = __int_as_float(e6.y), w7 = __int_as_float(e7.y);
    a0.x = fmaf(w0, bf_lo(u0), a0.x); a0.y = fmaf(w0, bf_hi(u0), a0.y);
    a1.x = fmaf(w1, bf_lo(u1), a1.x); a1.y = fmaf(w1, bf_hi(u1), a1.y);
    a2.x = fmaf(w2, bf_lo(u2), a2.x); a2.y = fmaf(w2, bf_hi(u2), a2.y);
    a3.x = fmaf(w3, bf_lo(u3), a3.x); a3.y = fmaf(w3, bf_hi(u3), a3.y);
    a4.x = fmaf(w4, bf_lo(u4), a4.x); a4.y = fmaf(w4, bf_hi(u4), a4.y);
    a5.x = fmaf(w5, bf_lo(u5), a5.x); a5.y = fmaf(w5, bf_hi(u5), a5.y);
    a6.x = fmaf(w6, bf_lo(u6), a6.x); a6.y = fmaf(w6, bf_hi(u6), a6.y);
    a7.x = fmaf(w7, bf_lo(u7), a7.x); a7.y = fmaf(w7, bf_hi(u7), a7.y);
    sd += ((w0 + w1) + (w2 + w3)) + ((w4 + w5) + (w6 + w7));
  }
  for (; p < p1; ++p) {
    int2 e = edata[p];
    uint u = *(const uint*)(const void*)(gb + (size_t)e.x * 128);
    float w = __int_as_float(e.y);
    a0.x = fmaf(w, bf_lo(u), a0.x); a0.y = fmaf(w, bf_hi(u), a0.y);
    sd += w;
  }
  float ax = ((a0.x + a1.x) + (a2.x + a3.x)) + ((a4.x + a5.x) + (a6.x + a7.x));
  float ay = ((a0.y + a1.y) + (a2.y + a3.y)) + ((a4.y + a5.y) + (a6.y + a7.y));

  float di = dinv[node];
  uint us = *(const uint*)(const void*)(gb + (size_t)node * 128);
  ax = (ax + di * bf_lo(us)) * di;
  ay = (ay + di * bf_hi(us)) * di;
  float si = (sd + di) * di;

  float2 st; st.x = ax; st.y = ay;
  *(float2*)(xa + (size_t)node * 128 + 2 * lane) = st;
  if (lane == 0) sarr[node] = si;
}

// ========== mega kernel: 3 fused MFMA GEMMs + full gating epilogue ==========
// H_hp = relu((x-xa)@W_hp^T + (1-s)b_hp); H_lp = relu(xa@W_lp^T + s*b_lp);
// H_i = relu(x@W_i^T + b_i); out = a_h*H_hp + a_l*H_lp + a_i*H_i.
// 256 thr = 4 waves x 16-row tiles. W_m fp32->bf16 into 32KB swizzled LDS.
__global__ __launch_bounds__(256) void k_mega(
    const float* __restrict__ x, const float* __restrict__ xa,
    const float* __restrict__ sarr,
    const float* __restrict__ W0, const float* __restrict__ W1,
    const float* __restrict__ W2,
    const float* __restrict__ b_hp, const float* __restrict__ b_lp,
    const float* __restrict__ b_i,
    const float* __restrict__ wlh, const float* __restrict__ wll,
    const float* __restrict__ wli,
    const float* __restrict__ pbh, const float* __restrict__ pbl,
    const float* __restrict__ pbi,
    float* __restrict__ out, int N) {
  __shared__ ushort Wl[16384];
  int tid = (int)threadIdx.x;
  int lane = tid & 63, wv = tid >> 6;
  int r = lane & 15, g = lane >> 4;
  int NT = N >> 4;
  int t = (int)blockIdx.x * 4 + wv;
  bool active = t < NT;

  bf16x8 Ax[4], Ad[4], Aa[4];
  float sj[4];
  if (active) {
    const float* xp = x + ((size_t)t * 16 + r) * 128 + g * 8;
    const float* ap = xa + ((size_t)t * 16 + r) * 128 + g * 8;
#pragma unroll
    for (int kc = 0; kc < 4; ++kc) {
      float4 v0 = *(const float4*)(xp + kc * 32);
      float4 v1 = *(const float4*)(xp + kc * 32 + 4);
      float4 w0 = *(const float4*)(ap + kc * 32);
      float4 w1 = *(const float4*)(ap + kc * 32 + 4);
      ushort8v ux, ud, ua;
      ux[0] = f2b(v0.x); ux[1] = f2b(v0.y); ux[2] = f2b(v0.z); ux[3] = f2b(v0.w);
      ux[4] = f2b(v1.x); ux[5] = f2b(v1.y); ux[6] = f2b(v1.z); ux[7] = f2b(v1.w);
      ud[0] = f2b(v0.x - w0.x); ud[1] = f2b(v0.y - w0.y);
      ud[2] = f2b(v0.z - w0.z); ud[3] = f2b(v0.w - w0.w);
      ud[4] = f2b(v1.x - w1.x); ud[5] = f2b(v1.y - w1.y);
      ud[6] = f2b(v1.z - w1.z); ud[7] = f2b(v1.w - w1.w);
      ua[0] = f2b(w0.x); ua[1] = f2b(w0.y); ua[2] = f2b(w0.z); ua[3] = f2b(w0.w);
      ua[4] = f2b(w1.x); ua[5] = f2b(w1.y); ua[6] = f2b(w1.z); ua[7] = f2b(w1.w);
      Ax[kc] = __builtin_bit_cast(bf16x8, ux);
      Ad[kc] = __builtin_bit_cast(bf16x8, ud);
      Aa[kc] = __builtin_bit_cast(bf16x8, ua);
    }
#pragma unroll
    for (int j = 0; j < 4; ++j) sj[j] = sarr[t * 16 + 4 * g + j];
  }

  f32x4 aH[8], aL[8], aI[8];
  if (active) {
#pragma unroll
    for (int ct = 0; ct < 8; ++ct) {
      float bh = b_hp[ct * 16 + r], bl = b_lp[ct * 16 + r], bi = b_i[ct * 16 + r];
#pragma unroll
      for (int j = 0; j < 4; ++j) {
        aH[ct][j] = (1.f - sj[j]) * bh;
        aL[ct][j] = sj[j] * bl;
        aI[ct][j] = bi;
      }
    }
  }

  for (int m = 0; m < 3; ++m) {
    const float* Wsrc = (m == 0) ? W0 : (m == 1) ? W1 : W2;
    __syncthreads();
    for (int i = tid; i < 2048; i += 256) {
      int byte = i << 4;
      int row = byte >> 8;
      int swz = byte ^ ((row & 7) << 4);
      const float* s = Wsrc + (i << 3);
      float4 v0 = *(const float4*)s;
      float4 v1 = *(const float4*)(s + 4);
      ushort8v u;
      u[0] = f2b(v0.x); u[1] = f2b(v0.y); u[2] = f2b(v0.z); u[3] = f2b(v0.w);
      u[4] = f2b(v1.x); u[5] = f2b(v1.y); u[6] = f2b(v1.z); u[7] = f2b(v1.w);
      *(ushort8v*)((char*)Wl + swz) = u;
    }
    __syncthreads();
    if (!active) continue;
#pragma unroll
    for (int kc = 0; kc < 4; ++kc)
#pragma unroll
      for (int ct = 0; ct < 8; ++ct) {
        int row = ct * 16 + r;
        int byte = row * 256 + kc * 64 + g * 16;
        int swz = byte ^ ((row & 7) << 4);
        bf16x8 B = *(const bf16x8*)((const char*)Wl + swz);
        if (m == 0)      aH[ct] = __builtin_amdgcn_mfma_f32_16x16x32_bf16(Ad[kc], B, aH[ct], 0, 0, 0);
        else if (m == 1) aL[ct] = __builtin_amdgcn_mfma_f32_16x16x32_bf16(Aa[kc], B, aL[ct], 0, 0, 0);
        else             aI[ct] = __builtin_amdgcn_mfma_f32_16x16x32_bf16(Ax[kc], B, aI[ct], 0, 0, 0);
      }
  }
  if (!active) return;

  // epilogue: relu, three 128-dots per row (shfl-reduce over 16 lanes), gate
  float dh[4] = {0,0,0,0}, dl[4] = {0,0,0,0}, dd[4] = {0,0,0,0};
#pragma unroll
  for (int ct = 0; ct < 8; ++ct) {
    float wh = wlh[ct * 16 + r], wl = wll[ct * 16 + r], wi = wli[ct * 16 + r];
#pragma unroll
    for (int j = 0; j < 4; ++j) {
      float Hh = fmaxf(aH[ct][j], 0.f);
      float Hl = fmaxf(aL[ct][j], 0.f);
      float Hi = fmaxf(aI[ct][j], 0.f);
      aH[ct][j] = Hh; aL[ct][j] = Hl; aI[ct][j] = Hi;
      dh[j] = fmaf(Hh, wh, dh[j]);
      dl[j] = fmaf(Hl, wl, dl[j]);
      dd[j] = fmaf(Hi, wi, dd[j]);
    }
  }
#pragma unroll
  for (int o = 1; o <= 8; o <<= 1) {
#pragma unroll
    for (int j = 0; j < 4; ++j) {
      dh[j] += __shfl_xor(dh[j], o);
      dl[j] += __shfl_xor(dl[j], o);
      dd[j] += __shfl_xor(dd[j], o);
    }
  }
  float bh0 = pbh[0], bl0 = pbl[0], bi0 = pbi[0];
  float ah[4], al[4], ai[4];
#pragma unroll
  for (int j = 0; j < 4; ++j) {
    ah[j] = 1.f / (1.f + __expf(-(dh[j] + bh0)));
    al[j] = 1.f / (1.f + __expf(-(dl[j] + bl0)));
    ai[j] = 1.f / (1.f + __expf(-(dd[j] + bi0)));
  }
#pragma unroll
  for (int ct = 0; ct < 8; ++ct)
#pragma unroll
    for (int j = 0; j < 4; ++j) {
      float v = ah[j] * aH[ct][j] + al[j] * aL[ct][j] + ai[j] * aI[ct][j];
      out[(size_t)(t * 16 + 4 * g + j) * 128 + ct * 16 + r] = v;
    }
}

// ================= launch ===================================================
extern "C" void kernel_launch(void* const* d_in, const int* in_sizes, int n_in,
                              void* d_out, int out_size, void* d_ws, size_t ws_size,
                              hipStream_t stream) {
  const float* x     = (const float*)d_in[0];
  const int*   ei    = (const int*)d_in[1];
  const float* W_hp  = (const float*)d_in[2];
  const float* b_hp  = (const float*)d_in[3];
  const float* W_lp  = (const float*)d_in[4];
  const float* b_lp  = (const float*)d_in[5];
  const float* W_i   = (const float*)d_in[6];
  const float* b_i   = (const float*)d_in[7];
  const float* wlh   = (const float*)d_in[8];
  const float* pbh   = (const float*)d_in[9];
  const float* wll   = (const float*)d_in[10];
  const float* pbl   = (const float*)d_in[11];
  const float* wli   = (const float*)d_in[12];
  const float* pbi   = (const float*)d_in[13];
  float* out = (float*)d_out;

  int N = in_sizes[0] / 128;
  int E = in_sizes[1] / 2;
  int NB = (N + 255) / 256;

  ushort* xb    = (ushort*)d_ws;                    // N*128 bf16
  float*  xa    = (float*)(xb + (size_t)N * 128);   // N*128 f32
  float*  sarr  = xa + (size_t)N * 128;             // N
  int2*   edata = (int2*)(sarr + N);                // E
  float*  dinv  = (float*)(edata + E);              // N
  int*    cnt   = (int*)(dinv + N);                 // N
  int*    off   = cnt + N;                          // N+1
  int*    cursor= off + N + 1;                      // N
  int*    btot  = cursor + N;                       // 256

  int nCV = 512;  // cvt blocks

  hipMemsetAsync(cnt, 0, sizeof(int) * N, stream);
  k_cvt_count<<<nCV + (E + 255) / 256, 256, 0, stream>>>(
      x, xb, N * 16, ei + E, cnt, E, nCV);
  k_scanA<<<NB, 256, 0, stream>>>(cnt, off, dinv, btot, N);
  k_scanBC<<<NB, 256, 0, stream>>>(off, btot, cursor, N, E, NB);
  k_scatter<<<(E + 255) / 256, 256, 0, stream>>>(ei, dinv, cursor, edata, E);
  k_agg_x<<<(N + 3) / 4, 256, 0, stream>>>(xb, dinv, off, edata, xa, sarr, N);
  k_mega<<<(N / 16 + 3) / 4, 256, 0, stream>>>(
      x, xa, sarr, W_hp, W_lp, W_i, b_hp, b_lp, b_i,
      wlh, wll, wli, pbh, pbl, pbi, out, N);
}